// Round 10
// baseline (106.615 us; speedup 1.0000x reference)
//
#include <hip/hip_runtime.h>
#include <hip/hip_bf16.h>
#include <cstdint>
#include <cstddef>

typedef __attribute__((ext_vector_type(4))) float  f32x4;
typedef __attribute__((ext_vector_type(8))) short  short8;

// bf16 RNE via hardware cvt (compiler fuses pairs into v_cvt_pk_bf16_f32)
__device__ __forceinline__ short f2bf(float f) {
  __hip_bfloat16 h = __float2bfloat16(f);
  return *reinterpret_cast<short*>(&h);
}
__device__ __forceinline__ float sigmoidf(float x) {
  return 1.0f / (1.0f + __expf(-x));
}

// ---------------- pool: g[b,c] = mean_s x[b,c,s] -> bf16 --------------------
// 16 rows per 256-thread block: 784 contiguous float4 loads (dense, full
// lines), LDS scratch, deterministic per-row 49-way sums. 8192 blocks.
__global__ __launch_bounds__(256) void pool_kernel(const float* __restrict__ x,
                                                   short* __restrict__ g) {
  __shared__ float sums[784];
  const int tid = threadIdx.x;
  const f32x4* base = (const f32x4*)(x + (size_t)blockIdx.x * (16 * 196));
#pragma unroll
  for (int it = 0; it < 4; ++it) {
    int i = it * 256 + tid;
    if (it < 3 || tid < 16) {
      f32x4 v = base[i];
      sums[i] = v[0] + v[1] + v[2] + v[3];
    }
  }
  __syncthreads();
  if (tid < 16) {
    float s = 0.f;
#pragma unroll
    for (int j = 0; j < 49; ++j) s += sums[tid * 49 + j];
    g[blockIdx.x * 16 + tid] = f2bf(s * (1.0f / 196.0f));
  }
}

// --------- barrier-free GEMM body: out = act(A @ B^T + bias) ----------------
// A: [64][K] bf16, L2-resident -> loaded JUST-IN-TIME (saves 32 VGPR).
// B: [N][K] f32 streamed from HBM, 1-deep prefetch.
// WAVES waves split K; LDS reduce + bias + sigmoid epilogue. No HBM partials.
template<int N, int K, int WAVES, bool OUT_BF16, bool ZERO_FEAT>
__device__ __forceinline__ void gemm_body(const short* __restrict__ A,
                                          const float* __restrict__ B,
                                          const float* __restrict__ bias,
                                          void* __restrict__ outp,
                                          float* __restrict__ zbuf,
                                          float* __restrict__ red) {
  constexpr int KW = K / WAVES;    // k-range per wave
  constexpr int NK = KW / 32;      // MFMA k-steps per wave
  constexpr int NT = WAVES * 64;   // threads
  const int n0  = blockIdx.x * 16;
  const int tid = threadIdx.x;
  const int l   = tid & 63;
  const int wv  = tid >> 6;
  const int kw0 = wv * KW;

  if constexpr (ZERO_FEAT) {       // 512 blocks x 98 = 50176 floats
    if (tid < 98) zbuf[blockIdx.x * 98 + tid] = 0.f;
  }

  const int ko = (l >> 4) * 8;     // k-offset within 32-k step (operand layout)
  const float* Bp = B + (size_t)(n0 + (l & 15)) * K + kw0 + ko;
  const short* Ap = A + (size_t)(l & 15) * K + kw0 + ko;

  f32x4 acc0 = {}, acc1 = {}, acc2 = {}, acc3 = {};

  // prefetch B for t=0
  f32x4 bc0 = *(const f32x4*)(Bp);
  f32x4 bc1 = *(const f32x4*)(Bp + 4);

  for (int t = 0; t < NK; ++t) {
    f32x4 bn0 = {}, bn1 = {};
    if (t + 1 < NK) {              // 1-deep HBM prefetch of next B chunk
      const float* bp = Bp + (t + 1) * 32;
      bn0 = *(const f32x4*)(bp);
      bn1 = *(const f32x4*)(bp + 4);
    }
    // A just-in-time (L2 hit ~200cy, hidden by other waves)
    const short* ap = Ap + t * 32;
    short8 ac0 = *(const short8*)(ap);
    short8 ac1 = *(const short8*)(ap + 16 * K);
    short8 ac2 = *(const short8*)(ap + 32 * K);
    short8 ac3 = *(const short8*)(ap + 48 * K);
    short8 bb;
    bb[0] = f2bf(bc0[0]); bb[1] = f2bf(bc0[1]); bb[2] = f2bf(bc0[2]); bb[3] = f2bf(bc0[3]);
    bb[4] = f2bf(bc1[0]); bb[5] = f2bf(bc1[1]); bb[6] = f2bf(bc1[2]); bb[7] = f2bf(bc1[3]);
    acc0 = __builtin_amdgcn_mfma_f32_16x16x32_bf16(ac0, bb, acc0, 0, 0, 0);
    acc1 = __builtin_amdgcn_mfma_f32_16x16x32_bf16(ac1, bb, acc1, 0, 0, 0);
    acc2 = __builtin_amdgcn_mfma_f32_16x16x32_bf16(ac2, bb, acc2, 0, 0, 0);
    acc3 = __builtin_amdgcn_mfma_f32_16x16x32_bf16(ac3, bb, acc3, 0, 0, 0);
    bc0 = bn0; bc1 = bn1;
  }

  // wave-partial -> LDS (C/D layout: m = mi*16 + (l>>4)*4 + r, n = l&15)
  {
    float* rw = red + wv * 1024;
    const int mb = (l >> 4) << 2;
    const int nn = l & 15;
#pragma unroll
    for (int r = 0; r < 4; ++r) rw[(0  + mb + r) * 16 + nn] = acc0[r];
#pragma unroll
    for (int r = 0; r < 4; ++r) rw[(16 + mb + r) * 16 + nn] = acc1[r];
#pragma unroll
    for (int r = 0; r < 4; ++r) rw[(32 + mb + r) * 16 + nn] = acc2[r];
#pragma unroll
    for (int r = 0; r < 4; ++r) rw[(48 + mb + r) * 16 + nn] = acc3[r];
  }
  __syncthreads();

  // reduce WAVES wave-partials + bias + sigmoid, write final
#pragma unroll
  for (int i = tid; i < 1024; i += NT) {
    float s = 0.f;
#pragma unroll
    for (int w = 0; w < WAVES; ++w) s += red[w * 1024 + i];
    int m  = i >> 4;
    int nn = n0 + (i & 15);
    s = sigmoidf(s + bias[nn]);
    if constexpr (OUT_BF16) ((short*)outp)[(size_t)m * N + nn] = f2bf(s);
    else                    ((float*)outp)[(size_t)m * N + nn] = s;
  }
}

// GEMM1: 16 waves (1024 threads), 256 blocks -> 16 waves/CU
__global__ __launch_bounds__(1024, 4) void gemm1_kernel(const short* __restrict__ A,
                                                        const float* __restrict__ B,
                                                        const float* __restrict__ bias,
                                                        short* __restrict__ outp) {
  __shared__ float red[16 * 1024];
  gemm_body<4096, 2048, 16, true, false>(A, B, bias, outp, nullptr, red);
}

// GEMM2: 8 waves (512 threads), 512 blocks; min 6 waves/EU -> 3 blocks/CU
// (VGPR cap 85; JIT-A keeps live set ~80). Also zeroes feat for einsum.
__global__ __launch_bounds__(512, 6) void gemm2_kernel(const short* __restrict__ A,
                                                       const float* __restrict__ B,
                                                       const float* __restrict__ bias,
                                                       float* __restrict__ outp,
                                                       float* __restrict__ zbuf) {
  __shared__ float red[8 * 1024];
  gemm_body<8192, 4096, 8, false, true>(A, B, bias, outp, zbuf, red);
}

// --------- einsum: feat[b,p,s] += (1/C) sum_{c in chunk} w[b,p,c] x[b,c,s] --
// grid = 64 b x 16 c-chunks, one wave per block. Lane t<49 owns s=4t..4t+3
// (f32x4 loads, 16B/lane, unroll 8 -> 8 loads in flight). Gates via SGPR
// (blockIdx-uniform addresses). feat pre-zeroed by GEMM2; 16 atomics/elem.
__global__ __launch_bounds__(64) void einsum_kernel(const float* __restrict__ x,
                                                    const float* __restrict__ wg,
                                                    float* __restrict__ feat) {
  const int b  = blockIdx.x >> 4;
  const int cc = blockIdx.x & 15;
  const int t  = threadIdx.x;
  if (t >= 49) return;
  const float* wp = wg + (size_t)b * 8192 + cc * 128;   // + p*2048 + c (uniform)
  const float* xp = x + (size_t)b * 2048 * 196 + (size_t)cc * 128 * 196 + 4 * t;
  f32x4 a0 = {}, a1 = {}, a2 = {}, a3 = {};
#pragma unroll 8
  for (int c = 0; c < 128; ++c) {
    f32x4 xv = *(const f32x4*)(xp + (size_t)c * 196);
    float w0 = wp[c], w1 = wp[2048 + c], w2 = wp[4096 + c], w3 = wp[6144 + c];
#pragma unroll
    for (int j = 0; j < 4; ++j) {
      a0[j] = __builtin_fmaf(w0, xv[j], a0[j]);
      a1[j] = __builtin_fmaf(w1, xv[j], a1[j]);
      a2[j] = __builtin_fmaf(w2, xv[j], a2[j]);
      a3[j] = __builtin_fmaf(w3, xv[j], a3[j]);
    }
  }
  const float invC = 1.0f / 2048.0f;
  float* fb = feat + (size_t)b * 4 * 196 + 4 * t;
#pragma unroll
  for (int j = 0; j < 4; ++j) {
    atomicAdd(fb + 0 * 196 + j, a0[j] * invC);
    atomicAdd(fb + 1 * 196 + j, a1[j] * invC);
    atomicAdd(fb + 2 * 196 + j, a2[j] * invC);
    atomicAdd(fb + 3 * 196 + j, a3[j] * invC);
  }
}

extern "C" void kernel_launch(void* const* d_in, const int* in_sizes, int n_in,
                              void* d_out, int out_size, void* d_ws, size_t ws_size,
                              hipStream_t stream) {
  const float* x  = (const float*)d_in[0];   // [64,2048,14,14]
  const float* w1 = (const float*)d_in[1];   // [4096,2048]
  const float* b1 = (const float*)d_in[2];   // [4096]
  const float* w2 = (const float*)d_in[3];   // [8192,4096]
  const float* b2 = (const float*)d_in[4];   // [8192]
  float* out = (float*)d_out;

  short* g_bf = (short*)d_ws;                // 64*2048 bf16 (256 KB)
  short* h_bf = g_bf + 64 * 2048;            // 64*4096 bf16 (512 KB)

  float* wout = out;                         // [64, 8192] == [B,P,C] flat
  float* feat = out + 524288;                // [64, 4, 196]

  // 1) pool -> g (bf16): 8192 blocks x 16 rows
  pool_kernel<<<8192, 256, 0, stream>>>(x, g_bf);

  // 2) GEMM1: h = sigmoid(g @ w1^T + b1), bf16 out (256 blocks x 16 waves)
  gemm1_kernel<<<4096 / 16, 1024, 0, stream>>>(g_bf, w1, b1, h_bf);

  // 3) GEMM2: w = sigmoid(h @ w2^T + b2), f32 out; also zeroes feat
  gemm2_kernel<<<8192 / 16, 512, 0, stream>>>(h_bf, w2, b2, wout, feat);

  // 4) einsum -> feat (atomic accumulate over 16 c-chunks)
  einsum_kernel<<<64 * 16, 64, 0, stream>>>(x, wout, feat);
}

// Round 11
// 97.689 us; speedup vs baseline: 1.0914x; 1.0914x over previous
//
#include <hip/hip_runtime.h>
#include <hip/hip_bf16.h>
#include <cstdint>
#include <cstddef>

typedef __attribute__((ext_vector_type(4))) float  f32x4;
typedef __attribute__((ext_vector_type(8))) short  short8;

// bf16 RNE via hardware cvt (compiler fuses pairs into v_cvt_pk_bf16_f32)
__device__ __forceinline__ short f2bf(float f) {
  __hip_bfloat16 h = __float2bfloat16(f);
  return *reinterpret_cast<short*>(&h);
}
__device__ __forceinline__ float sigmoidf(float x) {
  return 1.0f / (1.0f + __expf(-x));
}

// ---------------- pool: g[b,c] = mean_s x[b,c,s] -> bf16 --------------------
// 16 rows per 256-thread block: 784 contiguous float4 loads (dense, full
// lines), LDS scratch, deterministic per-row 49-way sums. 8192 blocks.
__global__ __launch_bounds__(256) void pool_kernel(const float* __restrict__ x,
                                                   short* __restrict__ g) {
  __shared__ float sums[784];
  const int tid = threadIdx.x;
  const f32x4* base = (const f32x4*)(x + (size_t)blockIdx.x * (16 * 196));
#pragma unroll
  for (int it = 0; it < 4; ++it) {
    int i = it * 256 + tid;
    if (it < 3 || tid < 16) {
      f32x4 v = base[i];
      sums[i] = v[0] + v[1] + v[2] + v[3];
    }
  }
  __syncthreads();
  if (tid < 16) {
    float s = 0.f;
#pragma unroll
    for (int j = 0; j < 49; ++j) s += sums[tid * 49 + j];
    g[blockIdx.x * 16 + tid] = f2bf(s * (1.0f / 196.0f));
  }
}

// --------- barrier-free GEMM body: out = act(A @ B^T + bias) ----------------
// A: [64][K] bf16 (L2-resident), B: [N][K] f32 streamed to regs, both with
// 1-iteration-deep prefetch (R9-proven structure).
// WAVES waves split K; LDS reduce + bias + sigmoid epilogue. No HBM partials.
template<int N, int K, int WAVES, bool OUT_BF16, bool ZERO_FEAT>
__device__ __forceinline__ void gemm_body(const short* __restrict__ A,
                                          const float* __restrict__ B,
                                          const float* __restrict__ bias,
                                          void* __restrict__ outp,
                                          float* __restrict__ zbuf,
                                          float* __restrict__ red) {
  constexpr int KW = K / WAVES;    // k-range per wave
  constexpr int NK = KW / 32;      // MFMA k-steps per wave
  constexpr int NT = WAVES * 64;   // threads
  const int n0  = blockIdx.x * 16;
  const int tid = threadIdx.x;
  const int l   = tid & 63;
  const int wv  = tid >> 6;
  const int kw0 = wv * KW;

  if constexpr (ZERO_FEAT) {       // 512 blocks x 98 = 50176 floats
    if (tid < 98) zbuf[blockIdx.x * 98 + tid] = 0.f;
  }

  const int ko = (l >> 4) * 8;     // k-offset within 32-k step (operand layout)
  const float* Bp = B + (size_t)(n0 + (l & 15)) * K + kw0 + ko;
  const short* Ap = A + (size_t)(l & 15) * K + kw0 + ko;

  f32x4 acc0 = {}, acc1 = {}, acc2 = {}, acc3 = {};

  // prefetch t=0
  f32x4 bc0 = *(const f32x4*)(Bp);
  f32x4 bc1 = *(const f32x4*)(Bp + 4);
  short8 ac0 = *(const short8*)(Ap);
  short8 ac1 = *(const short8*)(Ap + 16 * K);
  short8 ac2 = *(const short8*)(Ap + 32 * K);
  short8 ac3 = *(const short8*)(Ap + 48 * K);

  for (int t = 0; t < NK; ++t) {
    f32x4 bn0 = {}, bn1 = {};
    short8 an0 = {}, an1 = {}, an2 = {}, an3 = {};
    if (t + 1 < NK) {              // issue next k-step loads early
      const float* bp = Bp + (t + 1) * 32;
      const short* ap = Ap + (t + 1) * 32;
      bn0 = *(const f32x4*)(bp);
      bn1 = *(const f32x4*)(bp + 4);
      an0 = *(const short8*)(ap);
      an1 = *(const short8*)(ap + 16 * K);
      an2 = *(const short8*)(ap + 32 * K);
      an3 = *(const short8*)(ap + 48 * K);
    }
    short8 bb;
    bb[0] = f2bf(bc0[0]); bb[1] = f2bf(bc0[1]); bb[2] = f2bf(bc0[2]); bb[3] = f2bf(bc0[3]);
    bb[4] = f2bf(bc1[0]); bb[5] = f2bf(bc1[1]); bb[6] = f2bf(bc1[2]); bb[7] = f2bf(bc1[3]);
    acc0 = __builtin_amdgcn_mfma_f32_16x16x32_bf16(ac0, bb, acc0, 0, 0, 0);
    acc1 = __builtin_amdgcn_mfma_f32_16x16x32_bf16(ac1, bb, acc1, 0, 0, 0);
    acc2 = __builtin_amdgcn_mfma_f32_16x16x32_bf16(ac2, bb, acc2, 0, 0, 0);
    acc3 = __builtin_amdgcn_mfma_f32_16x16x32_bf16(ac3, bb, acc3, 0, 0, 0);
    bc0 = bn0; bc1 = bn1;
    ac0 = an0; ac1 = an1; ac2 = an2; ac3 = an3;
  }

  // wave-partial -> LDS (C/D layout: m = mi*16 + (l>>4)*4 + r, n = l&15)
  {
    float* rw = red + wv * 1024;
    const int mb = (l >> 4) << 2;
    const int nn = l & 15;
#pragma unroll
    for (int r = 0; r < 4; ++r) rw[(0  + mb + r) * 16 + nn] = acc0[r];
#pragma unroll
    for (int r = 0; r < 4; ++r) rw[(16 + mb + r) * 16 + nn] = acc1[r];
#pragma unroll
    for (int r = 0; r < 4; ++r) rw[(32 + mb + r) * 16 + nn] = acc2[r];
#pragma unroll
    for (int r = 0; r < 4; ++r) rw[(48 + mb + r) * 16 + nn] = acc3[r];
  }
  __syncthreads();

  // reduce WAVES wave-partials + bias + sigmoid, write final
#pragma unroll
  for (int i = tid; i < 1024; i += NT) {
    float s = 0.f;
#pragma unroll
    for (int w = 0; w < WAVES; ++w) s += red[w * 1024 + i];
    int m  = i >> 4;
    int nn = n0 + (i & 15);
    s = sigmoidf(s + bias[nn]);
    if constexpr (OUT_BF16) ((short*)outp)[(size_t)m * N + nn] = f2bf(s);
    else                    ((float*)outp)[(size_t)m * N + nn] = s;
  }
}

// GEMM1: 16 waves (1024 threads), 256 blocks -> 16 waves/CU
__global__ __launch_bounds__(1024, 4) void gemm1_kernel(const short* __restrict__ A,
                                                        const float* __restrict__ B,
                                                        const float* __restrict__ bias,
                                                        short* __restrict__ outp) {
  __shared__ float red[16 * 1024];
  gemm_body<4096, 2048, 16, true, false>(A, B, bias, outp, nullptr, red);
}

// GEMM2: 8 waves (512 threads), 512 blocks -> 2 blocks/CU; also zeroes feat
__global__ __launch_bounds__(512, 4) void gemm2_kernel(const short* __restrict__ A,
                                                       const float* __restrict__ B,
                                                       const float* __restrict__ bias,
                                                       float* __restrict__ outp,
                                                       float* __restrict__ zbuf) {
  __shared__ float red[8 * 1024];
  gemm_body<8192, 4096, 8, false, true>(A, B, bias, outp, zbuf, red);
}

// --------- einsum: feat[b,p,s] += (1/C) sum_{c in chunk} w[b,p,c] x[b,c,s] --
// grid = 64 b x 16 c-chunks. Gate values read at loop-uniform addresses ->
// scalar (SGPR) loads; inner loop = 1 vector load + 4 v_fmac(v,s,v).
// feat pre-zeroed by GEMM2; 16-way atomicAdd per element.
__global__ __launch_bounds__(256) void einsum_kernel(const float* __restrict__ x,
                                                     const float* __restrict__ wg,
                                                     float* __restrict__ feat) {
  const int b   = blockIdx.x >> 4;
  const int cc  = blockIdx.x & 15;
  const int tid = threadIdx.x;
  if (tid >= 196) return;
  const float* wp = wg + (size_t)b * 8192 + cc * 128;       // + p*2048 + c (uniform)
  const float* xp = x + (size_t)b * 2048 * 196 + (size_t)cc * 128 * 196 + tid;
  float a0 = 0.f, a1 = 0.f, a2 = 0.f, a3 = 0.f;
#pragma unroll 8
  for (int c = 0; c < 128; ++c) {
    float xv = xp[(size_t)c * 196];
    a0 = __builtin_fmaf(wp[c],        xv, a0);
    a1 = __builtin_fmaf(wp[2048 + c], xv, a1);
    a2 = __builtin_fmaf(wp[4096 + c], xv, a2);
    a3 = __builtin_fmaf(wp[6144 + c], xv, a3);
  }
  const float invC = 1.0f / 2048.0f;
  atomicAdd(feat + (b * 4 + 0) * 196 + tid, a0 * invC);
  atomicAdd(feat + (b * 4 + 1) * 196 + tid, a1 * invC);
  atomicAdd(feat + (b * 4 + 2) * 196 + tid, a2 * invC);
  atomicAdd(feat + (b * 4 + 3) * 196 + tid, a3 * invC);
}

extern "C" void kernel_launch(void* const* d_in, const int* in_sizes, int n_in,
                              void* d_out, int out_size, void* d_ws, size_t ws_size,
                              hipStream_t stream) {
  const float* x  = (const float*)d_in[0];   // [64,2048,14,14]
  const float* w1 = (const float*)d_in[1];   // [4096,2048]
  const float* b1 = (const float*)d_in[2];   // [4096]
  const float* w2 = (const float*)d_in[3];   // [8192,4096]
  const float* b2 = (const float*)d_in[4];   // [8192]
  float* out = (float*)d_out;

  short* g_bf = (short*)d_ws;                // 64*2048 bf16 (256 KB)
  short* h_bf = g_bf + 64 * 2048;            // 64*4096 bf16 (512 KB)

  float* wout = out;                         // [64, 8192] == [B,P,C] flat
  float* feat = out + 524288;                // [64, 4, 196]

  // 1) pool -> g (bf16): 8192 blocks x 16 rows
  pool_kernel<<<8192, 256, 0, stream>>>(x, g_bf);

  // 2) GEMM1: h = sigmoid(g @ w1^T + b1), bf16 out (256 blocks x 16 waves)
  gemm1_kernel<<<4096 / 16, 1024, 0, stream>>>(g_bf, w1, b1, h_bf);

  // 3) GEMM2: w = sigmoid(h @ w2^T + b2), f32 out; also zeroes feat
  gemm2_kernel<<<8192 / 16, 512, 0, stream>>>(h_bf, w2, b2, wout, feat);

  // 4) einsum -> feat (atomic accumulate over 16 c-chunks)
  einsum_kernel<<<64 * 16, 256, 0, stream>>>(x, wout, feat);
}